// Round 1
// baseline (560.294 us; speedup 1.0000x reference)
//
#include <hip/hip_runtime.h>
#include <cstdint>

#define S_LEN   2048
#define BATCH   4
#define NHEADS  4
#define HDIM    256
#define DDIM    1024
#define FOURD   4096
#define NCH     4096                    // B*NH*HD channels
#define PLANE   (S_LEN * NCH)           // per-gate plane: 8,388,608 floats
#define EPS     1e-8f

using bf16x8 = __attribute__((ext_vector_type(8))) short;
using f32x4  = __attribute__((ext_vector_type(4))) float;

__device__ __forceinline__ short f2bf(float f) {
  // fp32 -> bf16 round-to-nearest-even
  uint32_t u = __builtin_bit_cast(uint32_t, f);
  u += 0x7fffu + ((u >> 16) & 1u);
  return (short)(u >> 16);
}

// ---------------------------------------------------------------------------
// Kernel 1: gate projection. 16 GEMMs of [8192,256] x [256,256]^T.
// Grid: 1024 blocks (gh = bid&15, rowblk = bid>>4), 512 threads (8 waves).
// Each wave computes a 16-row x 256-col tile via 16x16x32 bf16 MFMA.
// W k-slice staged in LDS as bf16, padded stride 40 (2-way conflict = free).
// Gates written as 4 planes [g][s][b*1024 + h*256 + o] for coalesced access.
// ---------------------------------------------------------------------------
__global__ __launch_bounds__(512, 2) void gates_gemm(
    const float* __restrict__ x, const float* __restrict__ W,
    const float* __restrict__ bias, float* __restrict__ gates) {
  __shared__ unsigned short Wl[256 * 40];  // 20 KB

  const int bid    = blockIdx.x;
  const int gh     = bid & 15;       // g*4 + h
  const int rowblk = bid >> 4;       // 0..63, 128 rows each
  const int g      = gh >> 2;
  const int h      = gh & 3;
  const int tid    = threadIdx.x;
  const int wave   = tid >> 6;
  const int lane   = tid & 63;
  const int l16    = lane & 15;
  const int quad   = lane >> 4;
  const int m0     = rowblk * 128 + wave * 16;

  const float* Wg = W + (size_t)gh * 65536;

  // bias for this wave's 16 n-tiles
  float bv[16];
#pragma unroll
  for (int nt = 0; nt < 16; ++nt) bv[nt] = bias[gh * 256 + nt * 16 + l16];

  f32x4 acc[16];
#pragma unroll
  for (int nt = 0; nt < 16; ++nt) acc[nt] = (f32x4){0.f, 0.f, 0.f, 0.f};

  const int arow = m0 + l16;
  const float* abase = x + (size_t)arow * FOURD + g * DDIM + h * HDIM + quad * 8;

  for (int kt = 0; kt < 8; ++kt) {
    // prefetch A fragment (independent of LDS phase)
    float4 a01 = *(const float4*)(abase + kt * 32);
    float4 a23 = *(const float4*)(abase + kt * 32 + 4);

    __syncthreads();  // previous k-tile's LDS reads done
    // stage W[:, kt*32 : kt*32+32] as bf16 into LDS
#pragma unroll
    for (int it = 0; it < 4; ++it) {
      int f4i = tid + it * 512;        // 0..2047 float4s
      int o   = f4i >> 3;              // W row
      int kq  = f4i & 7;               // float4 within 32-k slice
      float4 w4 = *(const float4*)(Wg + (size_t)o * 256 + kt * 32 + kq * 4);
      ushort4 wb;
      wb.x = (unsigned short)f2bf(w4.x);
      wb.y = (unsigned short)f2bf(w4.y);
      wb.z = (unsigned short)f2bf(w4.z);
      wb.w = (unsigned short)f2bf(w4.w);
      *(ushort4*)&Wl[o * 40 + kq * 4] = wb;
    }
    __syncthreads();

    bf16x8 a;
    a[0] = f2bf(a01.x); a[1] = f2bf(a01.y); a[2] = f2bf(a01.z); a[3] = f2bf(a01.w);
    a[4] = f2bf(a23.x); a[5] = f2bf(a23.y); a[6] = f2bf(a23.z); a[7] = f2bf(a23.w);

#pragma unroll
    for (int nt = 0; nt < 16; ++nt) {
      int o = nt * 16 + l16;
      bf16x8 bfr = *(const bf16x8*)&Wl[o * 40 + quad * 8];
      acc[nt] = __builtin_amdgcn_mfma_f32_16x16x32_bf16(a, bfr, acc[nt], 0, 0, 0);
    }
  }

  // epilogue: C/D layout col=lane&15, row=quad*4+reg (m89-verified)
#pragma unroll
  for (int r = 0; r < 4; ++r) {
    int rowi = m0 + quad * 4 + r;
    int sx = rowi & (S_LEN - 1);
    int bx = rowi >> 11;
    float* dst = gates + (size_t)g * PLANE + (size_t)sx * NCH + bx * DDIM + h * HDIM;
#pragma unroll
    for (int nt = 0; nt < 16; ++nt) {
      dst[nt * 16 + l16] = acc[nt][r] + bv[nt];
    }
  }
}

// ---------------------------------------------------------------------------
// Kernel 2: elementwise stabilized scan over S=2048. One thread per channel
// (4096 channels). Double-buffered prefetch of 8 steps x 4 gates.
// ---------------------------------------------------------------------------
__global__ __launch_bounds__(64) void slstm_scan(
    const float* __restrict__ gates, float* __restrict__ out) {
  const int c  = blockIdx.x * 64 + threadIdx.x;   // 0..4095
  const float* gz = gates;
  const float* gi = gates + (size_t)PLANE;
  const float* gf = gates + 2 * (size_t)PLANE;
  const float* go = gates + 3 * (size_t)PLANE;
  const int b  = c >> 10;
  const int ch = c & 1023;
  float* hout = out + (size_t)b * (S_LEN * DDIM) + ch;

  float cs = 0.f, ns = 0.f, ms = 0.f, hv = 0.f;

  float z0[8], i0[8], f0[8], o0[8];
  float z1[8], i1[8], f1[8], o1[8];

#pragma unroll
  for (int j = 0; j < 8; ++j) {
    size_t off = (size_t)j * NCH + c;
    z0[j] = gz[off]; i0[j] = gi[off]; f0[j] = gf[off]; o0[j] = go[off];
  }

  auto step = [&](float zi, float ii, float fi, float oi, int s) {
    float lf  = __logf(__expf(fi) + EPS);
    float li  = __logf(__expf(ii) + EPS);
    float lfm = lf + ms;
    float mn  = fmaxf(lfm, li);
    float ih  = __expf(li - mn);
    float fh  = __expf(lfm - mn);
    float zv  = 1.f - 2.f * __builtin_amdgcn_rcpf(1.f + __expf(2.f * zi));
    float ov  = __builtin_amdgcn_rcpf(1.f + __expf(-oi));
    cs = fh * cs + ih * zv;
    ns = fh * ns + ih;
    ms = mn;
    hv = ov * cs * __builtin_amdgcn_rcpf(ns + EPS);
    hout[(size_t)s * DDIM] = hv;
  };

  for (int gb = 0; gb < 256; gb += 2) {
    // prefetch group gb+1 (always exists)
#pragma unroll
    for (int j = 0; j < 8; ++j) {
      size_t off = (size_t)((gb + 1) * 8 + j) * NCH + c;
      z1[j] = gz[off]; i1[j] = gi[off]; f1[j] = gf[off]; o1[j] = go[off];
    }
#pragma unroll
    for (int j = 0; j < 8; ++j) step(z0[j], i0[j], f0[j], o0[j], gb * 8 + j);

    if (gb + 2 < 256) {
#pragma unroll
      for (int j = 0; j < 8; ++j) {
        size_t off = (size_t)((gb + 2) * 8 + j) * NCH + c;
        z0[j] = gz[off]; i0[j] = gi[off]; f0[j] = gf[off]; o0[j] = go[off];
      }
    }
#pragma unroll
    for (int j = 0; j < 8; ++j) step(z1[j], i1[j], f1[j], o1[j], (gb + 1) * 8 + j);
  }

  // finals: h_f, c_f, n_f, m_f  (each [B,NH,HD] = channel-indexed)
  float* fin = out + (size_t)BATCH * S_LEN * DDIM;  // 8,388,608
  fin[c]            = hv;
  fin[NCH + c]      = cs;
  fin[2 * NCH + c]  = ns;
  fin[3 * NCH + c]  = ms;
}

extern "C" void kernel_launch(void* const* d_in, const int* in_sizes, int n_in,
                              void* d_out, int out_size, void* d_ws, size_t ws_size,
                              hipStream_t stream) {
  const float* x    = (const float*)d_in[0];   // [4,2048,4096] fp32
  const float* W    = (const float*)d_in[1];   // [4,4,256,256] fp32
  const float* bias = (const float*)d_in[2];   // [4,4,256] fp32
  float* out   = (float*)d_out;
  float* gates = (float*)d_ws;                 // 4 * PLANE floats = 134 MB

  gates_gemm<<<dim3(1024), dim3(512), 0, stream>>>(x, W, bias, gates);
  slstm_scan<<<dim3(64), dim3(64), 0, stream>>>(gates, out);
}

// Round 2
// 451.872 us; speedup vs baseline: 1.2399x; 1.2399x over previous
//
#include <hip/hip_runtime.h>
#include <cstdint>

#define S_LEN   2048
#define BATCH   4
#define NCH     4096                    // B*NH*HD channels
#define PLANE   ((size_t)S_LEN * NCH)   // per-gate plane: 8,388,608 floats
#define CHUNK   64
#define NCHUNK  32
#define SN      (NCHUNK * NCH)          // 131072 summary slots
#define EPS     1e-8f

using bf16x8 = __attribute__((ext_vector_type(8))) short;
using f32x4  = __attribute__((ext_vector_type(4))) float;
typedef unsigned short ushort_t;

__device__ __forceinline__ short f2bf(float f) {
  uint32_t u = __builtin_bit_cast(uint32_t, f);
  u += 0x7fffu + ((u >> 16) & 1u);
  return (short)(u >> 16);
}
__device__ __forceinline__ float bf2f(ushort_t u) {
  return __builtin_bit_cast(float, (uint32_t)u << 16);
}

// ---------------------------------------------------------------------------
// Kernel 1: gate projection, B-in-registers, no LDS, no barriers.
// Grid (16 gh, 2 nhalf, 16 rowgroup) x 512 thr. Wave owns one 16-col strip;
// loops 32 row-tiles of 16 rows with double-buffered A loads (fp32->bf16
// inline). Epilogue fuses tanh(z) / sigmoid(o); o stored bf16.
// ---------------------------------------------------------------------------
__global__ __launch_bounds__(512, 2) void gates_gemm2(
    const float* __restrict__ x, const float* __restrict__ W,
    const float* __restrict__ bias, float* __restrict__ gz /*3 fp32 planes*/,
    ushort_t* __restrict__ go) {
  const int gh  = blockIdx.x;          // g*4+h
  const int nh  = blockIdx.y;          // 0..1
  const int rg  = blockIdx.z;          // 0..15
  const int g   = gh >> 2, hh = gh & 3;
  const int tid = threadIdx.x;
  const int wave = tid >> 6, lane = tid & 63;
  const int l16 = lane & 15, quad = lane >> 4;
  const int n0  = (nh * 8 + wave) * 16;

  // B fragments: W[gh][n0+l16][kt*32 + quad*8 .. +8], held all kernel
  bf16x8 Bf[8];
  {
    const float* wp = W + ((size_t)gh << 16) + (n0 + l16) * 256 + quad * 8;
#pragma unroll
    for (int kt = 0; kt < 8; ++kt) {
      float4 w0 = *(const float4*)(wp + kt * 32);
      float4 w1 = *(const float4*)(wp + kt * 32 + 4);
      bf16x8 b;
      b[0] = f2bf(w0.x); b[1] = f2bf(w0.y); b[2] = f2bf(w0.z); b[3] = f2bf(w0.w);
      b[4] = f2bf(w1.x); b[5] = f2bf(w1.y); b[6] = f2bf(w1.z); b[7] = f2bf(w1.w);
      Bf[kt] = b;
    }
  }
  const float bv = bias[gh * 256 + n0 + l16];
  const int row0 = rg * 512;
  const float* ab = x + (size_t)(row0 + l16) * 4096 + g * 1024 + hh * 256 + quad * 8;

  float* plane = gz + (size_t)g * PLANE;  // valid for g<3

  float4 A0[16], A1[16];

  auto loadA = [&](float4* A, int r) {
    const float* p = ab + (size_t)r * 16 * 4096;
#pragma unroll
    for (int kt = 0; kt < 8; ++kt) {
      A[2 * kt]     = *(const float4*)(p + kt * 32);
      A[2 * kt + 1] = *(const float4*)(p + kt * 32 + 4);
    }
  };

  auto computeStore = [&](const float4* A, int r) {
    f32x4 acc = (f32x4){0.f, 0.f, 0.f, 0.f};
#pragma unroll
    for (int kt = 0; kt < 8; ++kt) {
      float4 a01 = A[2 * kt], a23 = A[2 * kt + 1];
      bf16x8 a;
      a[0] = f2bf(a01.x); a[1] = f2bf(a01.y); a[2] = f2bf(a01.z); a[3] = f2bf(a01.w);
      a[4] = f2bf(a23.x); a[5] = f2bf(a23.y); a[6] = f2bf(a23.z); a[7] = f2bf(a23.w);
      acc = __builtin_amdgcn_mfma_f32_16x16x32_bf16(a, Bf[kt], acc, 0, 0, 0);
    }
#pragma unroll
    for (int rr = 0; rr < 4; ++rr) {
      int rowi = row0 + r * 16 + quad * 4 + rr;
      int sx = rowi & (S_LEN - 1);
      int bx = rowi >> 11;
      size_t idx = (size_t)sx * NCH + bx * 1024 + hh * 256 + n0 + l16;
      float v = acc[rr] + bv;
      if (g == 0) {
        // tanh
        float t = 1.f - 2.f * __builtin_amdgcn_rcpf(1.f + __expf(2.f * v));
        plane[idx] = t;
      } else if (g == 3) {
        float s = __builtin_amdgcn_rcpf(1.f + __expf(-v));
        go[idx] = (ushort_t)f2bf(s);
      } else {
        plane[idx] = v;
      }
    }
  };

  loadA(A0, 0);
  for (int r = 0; r < 32; r += 2) {
    loadA(A1, r + 1);
    computeStore(A0, r);
    if (r + 2 < 32) loadA(A0, r + 2);
    computeStore(A1, r + 1);
  }
}

// ---------------------------------------------------------------------------
// Kernel 2: pass 1 — per (channel, chunk) locally-stabilized summaries.
// A = sum(f); B = max-scan(b + suffix-sum a) from -inf; D/Dn = stabilized
// c/n accumulators with zero entering state. All exp args <= 0.
// ---------------------------------------------------------------------------
__global__ __launch_bounds__(256) void scan_pass1(
    const float* __restrict__ gz, const float* __restrict__ gi,
    const float* __restrict__ gf, float* __restrict__ sums) {
  const int t  = blockIdx.x * 256 + threadIdx.x;   // 131072
  const int ch = t & (NCH - 1);
  const int ck = t >> 12;
  const size_t base = (size_t)ck * CHUNK * NCH + ch;

  float A = 0.f, Bv = -1e30f, D = 0.f, Dn = 0.f;

  float z0[8], i0[8], f0[8], z1[8], i1[8], f1[8];
#pragma unroll
  for (int j = 0; j < 8; ++j) {
    size_t off = base + (size_t)j * NCH;
    z0[j] = gz[off]; i0[j] = gi[off]; f0[j] = gf[off];
  }

  auto step = [&](float z, float i, float f) {
    float Bn = fmaxf(Bv + f, i);
    float e1 = __expf(Bv + f - Bn);
    float e2 = __expf(i - Bn);
    D  = e1 * D + e2 * z;
    Dn = e1 * Dn + e2;
    A += f;
    Bv = Bn;
  };

  for (int gb = 0; gb < 8; gb += 2) {
#pragma unroll
    for (int j = 0; j < 8; ++j) {
      size_t off = base + (size_t)((gb + 1) * 8 + j) * NCH;
      z1[j] = gz[off]; i1[j] = gi[off]; f1[j] = gf[off];
    }
#pragma unroll
    for (int j = 0; j < 8; ++j) step(z0[j], i0[j], f0[j]);
    if (gb + 2 < 8) {
#pragma unroll
      for (int j = 0; j < 8; ++j) {
        size_t off = base + (size_t)((gb + 2) * 8 + j) * NCH;
        z0[j] = gz[off]; i0[j] = gi[off]; f0[j] = gf[off];
      }
    }
#pragma unroll
    for (int j = 0; j < 8; ++j) step(z1[j], i1[j], f1[j]);
  }

  const int idx = ck * NCH + ch;
  sums[idx]          = A;
  sums[SN + idx]     = Bv;
  sums[2 * SN + idx] = D;
  sums[3 * SN + idx] = Dn;
}

// ---------------------------------------------------------------------------
// Kernel 3: pass 3 — fold preceding chunk summaries to get entering (c,n,m),
// then replay 64 steps of the original recurrence, writing h. Chunk 31 also
// writes finals.
// ---------------------------------------------------------------------------
__global__ __launch_bounds__(256) void scan_pass3(
    const float* __restrict__ gz, const float* __restrict__ gi,
    const float* __restrict__ gf, const ushort_t* __restrict__ go,
    const float* __restrict__ sums, float* __restrict__ out) {
  const int t  = blockIdx.x * 256 + threadIdx.x;
  const int ch = t & (NCH - 1);
  const int ck = t >> 12;     // uniform per block

  // entering state from summaries of chunks [0, ck)
  float c = 0.f, n = 0.f, m = 0.f;
  for (int k = 0; k < ck; ++k) {
    int idx = k * NCH + ch;
    float A  = sums[idx];
    float Bv = sums[SN + idx];
    float D  = sums[2 * SN + idx];
    float Dn = sums[3 * SN + idx];
    float mo = fmaxf(m + A, Bv);
    float ea = __expf(m + A - mo);
    float eb = __expf(Bv - mo);
    c = ea * c + eb * D;
    n = ea * n + eb * Dn;
    m = mo;
  }

  const int b = ch >> 10, d = ch & 1023;
  const size_t base = (size_t)ck * CHUNK * NCH + ch;
  float* hout = out + (size_t)b * (S_LEN * 1024) + (size_t)(ck * CHUNK) * 1024 + d;

  float hv = 0.f;
  float z0[8], i0[8], f0[8], o0[8], z1[8], i1[8], f1[8], o1[8];
#pragma unroll
  for (int j = 0; j < 8; ++j) {
    size_t off = base + (size_t)j * NCH;
    z0[j] = gz[off]; i0[j] = gi[off]; f0[j] = gf[off]; o0[j] = bf2f(go[off]);
  }

  auto step = [&](float z, float i, float f, float o, int s) {
    float mn = fmaxf(f + m, i);
    float fh = __expf(f + m - mn);
    float ih = __expf(i - mn);
    c = fh * c + ih * z;
    n = fh * n + ih;
    m = mn;
    hv = o * c * __builtin_amdgcn_rcpf(n + EPS);
    hout[(size_t)s * 1024] = hv;
  };

  for (int gb = 0; gb < 8; gb += 2) {
#pragma unroll
    for (int j = 0; j < 8; ++j) {
      size_t off = base + (size_t)((gb + 1) * 8 + j) * NCH;
      z1[j] = gz[off]; i1[j] = gi[off]; f1[j] = gf[off]; o1[j] = bf2f(go[off]);
    }
#pragma unroll
    for (int j = 0; j < 8; ++j) step(z0[j], i0[j], f0[j], o0[j], gb * 8 + j);
    if (gb + 2 < 8) {
#pragma unroll
      for (int j = 0; j < 8; ++j) {
        size_t off = base + (size_t)((gb + 2) * 8 + j) * NCH;
        z0[j] = gz[off]; i0[j] = gi[off]; f0[j] = gf[off]; o0[j] = bf2f(go[off]);
      }
    }
#pragma unroll
    for (int j = 0; j < 8; ++j) step(z1[j], i1[j], f1[j], o1[j], (gb + 1) * 8 + j);
  }

  if (ck == NCHUNK - 1) {
    float* fin = out + (size_t)BATCH * S_LEN * 1024;   // 8,388,608
    fin[ch]            = hv;
    fin[NCH + ch]      = c;
    fin[2 * NCH + ch]  = n;
    fin[3 * NCH + ch]  = m;
  }
}

extern "C" void kernel_launch(void* const* d_in, const int* in_sizes, int n_in,
                              void* d_out, int out_size, void* d_ws, size_t ws_size,
                              hipStream_t stream) {
  const float* x    = (const float*)d_in[0];   // [4,2048,4096] fp32
  const float* W    = (const float*)d_in[1];   // [4,4,256,256] fp32
  const float* bias = (const float*)d_in[2];   // [4,4,256] fp32
  float* out = (float*)d_out;

  // ws layout: z,i,f fp32 planes | o bf16 plane | sums (4*SN fp32)
  float*    gz   = (float*)d_ws;
  float*    gi   = gz + PLANE;
  float*    gf   = gz + 2 * PLANE;
  ushort_t* go   = (ushort_t*)(gz + 3 * PLANE);
  float*    sums = (float*)(go + PLANE);
  // total: 100.7 MB + 16.8 MB + 2.1 MB = 119.5 MB (< 134 MB proven to fit)

  gates_gemm2<<<dim3(16, 2, 16), dim3(512), 0, stream>>>(x, W, bias, gz, go);
  scan_pass1<<<dim3(512), dim3(256), 0, stream>>>(gz, gi, gf, sums);
  scan_pass3<<<dim3(512), dim3(256), 0, stream>>>(gz, gi, gf, go, sums, out);
}

// Round 3
// 277.907 us; speedup vs baseline: 2.0161x; 1.6260x over previous
//
#include <hip/hip_runtime.h>
#include <cstdint>

#define S_LEN   2048
#define BATCH   4
#define NCH     4096                    // B*NH*HD channels
#define PLANE   ((size_t)S_LEN * NCH)   // per-gate plane: 8,388,608 elems
#define CHUNK   32
#define NCHUNK  64
#define SN      ((size_t)NCHUNK * NCH)  // 262144 summary slots
#define EPS     1e-8f

using bf16x8 = __attribute__((ext_vector_type(8))) short;
using f32x4  = __attribute__((ext_vector_type(4))) float;
typedef unsigned short u16;

__device__ __forceinline__ short f2bf(float f) {
  uint32_t u = __builtin_bit_cast(uint32_t, f);
  u += 0x7fffu + ((u >> 16) & 1u);
  return (short)(u >> 16);
}
__device__ __forceinline__ float bf2f(u16 u) {
  return __builtin_bit_cast(float, (uint32_t)u << 16);
}

// ---------------------------------------------------------------------------
// Kernel 1: gate projection. Block = 1024 thr (16 waves) owns one (g,h) and
// 256 rows x all 256 cols (x read ONCE). A staged via double-buffered LDS
// bf16 tile (16x256, stride 264); wave w holds B for its 16-col strip in 32
// VGPRs. One barrier per 16-row tile. Epilogue fuses tanh(z)->bf16 and
// sigmoid(o)->bf16; i,f stored fp32.
// ---------------------------------------------------------------------------
__global__ __launch_bounds__(1024) void gates_gemm3(
    const float* __restrict__ x, const float* __restrict__ W,
    const float* __restrict__ bias,
    u16* __restrict__ gz16, float* __restrict__ gi, float* __restrict__ gf,
    u16* __restrict__ go16) {
  __shared__ u16 As[2][16 * 264];   // 2 x 8448 B

  const int gh  = blockIdx.x;          // g*4+h
  const int rg  = blockIdx.y;          // 0..31, 256 rows each
  const int g   = gh >> 2, hh = gh & 3;
  const int tid = threadIdx.x;
  const int wave = tid >> 6, lane = tid & 63;
  const int l16 = lane & 15, quad = lane >> 4;
  const int n0  = wave * 16;
  const int row0 = rg * 256;

  // B fragments for this wave's 16-col strip (held all kernel)
  bf16x8 Bf[8];
  {
    const float* wp = W + ((size_t)gh << 16) + (n0 + l16) * 256 + quad * 8;
#pragma unroll
    for (int kt = 0; kt < 8; ++kt) {
      float4 w0 = *(const float4*)(wp + kt * 32);
      float4 w1 = *(const float4*)(wp + kt * 32 + 4);
      bf16x8 b;
      b[0] = f2bf(w0.x); b[1] = f2bf(w0.y); b[2] = f2bf(w0.z); b[3] = f2bf(w0.w);
      b[4] = f2bf(w1.x); b[5] = f2bf(w1.y); b[6] = f2bf(w1.z); b[7] = f2bf(w1.w);
      Bf[kt] = b;
    }
  }
  const float bv = bias[gh * 256 + n0 + l16];

  // staging: thread loads float4 #tid of the tile (row = tid>>6, col4 = tid&63)
  const int sr = tid >> 6, sc = tid & 63;
  const float* sbase = x + (size_t)(row0 + sr) * 4096 + g * 1024 + hh * 256 + sc * 4;

  float4 sreg;
  auto gload = [&](int t) { sreg = *(const float4*)(sbase + (size_t)t * 16 * 4096); };
  auto swrite = [&](int buf) {
    ushort4 u;
    u.x = (u16)f2bf(sreg.x); u.y = (u16)f2bf(sreg.y);
    u.z = (u16)f2bf(sreg.z); u.w = (u16)f2bf(sreg.w);
    *(ushort4*)&As[buf][sr * 264 + sc * 4] = u;
  };

  gload(0); swrite(0);
  __syncthreads();

  for (int t = 0; t < 16; ++t) {
    if (t + 1 < 16) gload(t + 1);

    f32x4 acc = (f32x4){0.f, 0.f, 0.f, 0.f};
#pragma unroll
    for (int kt = 0; kt < 8; ++kt) {
      bf16x8 a = *(const bf16x8*)&As[t & 1][l16 * 264 + kt * 32 + quad * 8];
      acc = __builtin_amdgcn_mfma_f32_16x16x32_bf16(a, Bf[kt], acc, 0, 0, 0);
    }

    // epilogue (fire-and-forget stores, overlap with next staging)
#pragma unroll
    for (int rr = 0; rr < 4; ++rr) {
      int rowi = row0 + t * 16 + quad * 4 + rr;
      int sx = rowi & (S_LEN - 1);
      int bx = rowi >> 11;
      size_t idx = (size_t)sx * NCH + bx * 1024 + hh * 256 + n0 + l16;
      float v = acc[rr] + bv;
      if (g == 1)      gi[idx] = v;
      else if (g == 2) gf[idx] = v;
      else if (g == 0) {
        float tz = 1.f - 2.f * __builtin_amdgcn_rcpf(1.f + __expf(2.f * v));
        gz16[idx] = (u16)f2bf(tz);
      } else {
        float s = __builtin_amdgcn_rcpf(1.f + __expf(-v));
        go16[idx] = (u16)f2bf(s);
      }
    }

    if (t + 1 < 16) {
      swrite((t + 1) & 1);
      __syncthreads();
    }
  }
}

// ---------------------------------------------------------------------------
// Kernel 2: pass 1 — per (channel, 32-step chunk) locally-stabilized
// summaries: A = sum(f); B = stabilizer max-scan from -inf; D/Dn = c/n with
// zero entering state. 262144 threads.
// ---------------------------------------------------------------------------
__global__ __launch_bounds__(256) void scan_pass1(
    const u16* __restrict__ gz16, const float* __restrict__ gi,
    const float* __restrict__ gf, float* __restrict__ sums) {
  const int t  = blockIdx.x * 256 + threadIdx.x;   // 262144
  const int ch = t & (NCH - 1);
  const int ck = t >> 12;                           // 0..63
  const size_t base = (size_t)ck * CHUNK * NCH + ch;

  float A = 0.f, Bv = -1e30f, D = 0.f, Dn = 0.f;

  float z0[8], i0[8], f0[8], z1[8], i1[8], f1[8];
#pragma unroll
  for (int j = 0; j < 8; ++j) {
    size_t off = base + (size_t)j * NCH;
    z0[j] = bf2f(gz16[off]); i0[j] = gi[off]; f0[j] = gf[off];
  }

  auto step = [&](float z, float i, float f) {
    float Bn = fmaxf(Bv + f, i);
    float e1 = __expf(Bv + f - Bn);
    float e2 = __expf(i - Bn);
    D  = e1 * D + e2 * z;
    Dn = e1 * Dn + e2;
    A += f;
    Bv = Bn;
  };

  for (int gb = 0; gb < 4; gb += 2) {
#pragma unroll
    for (int j = 0; j < 8; ++j) {
      size_t off = base + (size_t)((gb + 1) * 8 + j) * NCH;
      z1[j] = bf2f(gz16[off]); i1[j] = gi[off]; f1[j] = gf[off];
    }
#pragma unroll
    for (int j = 0; j < 8; ++j) step(z0[j], i0[j], f0[j]);
    if (gb + 2 < 4) {
#pragma unroll
      for (int j = 0; j < 8; ++j) {
        size_t off = base + (size_t)((gb + 2) * 8 + j) * NCH;
        z0[j] = bf2f(gz16[off]); i0[j] = gi[off]; f0[j] = gf[off];
      }
    }
#pragma unroll
    for (int j = 0; j < 8; ++j) step(z1[j], i1[j], f1[j]);
  }

  const size_t idx = (size_t)ck * NCH + ch;
  sums[idx]          = A;
  sums[SN + idx]     = Bv;
  sums[2 * SN + idx] = D;
  sums[3 * SN + idx] = Dn;
}

// ---------------------------------------------------------------------------
// Kernel 3: pass 2 — one thread per channel folds the 64 chunk summaries,
// writing the entering (c,n,m) for every chunk. 4096 threads.
// ---------------------------------------------------------------------------
__global__ __launch_bounds__(256) void scan_pass2(
    const float* __restrict__ sums, float* __restrict__ ent) {
  const int ch = blockIdx.x * 256 + threadIdx.x;   // 0..4095
  float c = 0.f, n = 0.f, m = 0.f;

  float A0 = sums[ch], B0 = sums[SN + ch], D0 = sums[2 * SN + ch], N0 = sums[3 * SN + ch];
  for (int k = 0; k < NCHUNK; ++k) {
    float A1 = 0.f, B1 = 0.f, D1 = 0.f, N1 = 0.f;
    if (k + 1 < NCHUNK) {
      size_t ni = (size_t)(k + 1) * NCH + ch;
      A1 = sums[ni]; B1 = sums[SN + ni]; D1 = sums[2 * SN + ni]; N1 = sums[3 * SN + ni];
    }
    size_t idx = (size_t)k * NCH + ch;
    ent[idx]          = c;
    ent[SN + idx]     = n;
    ent[2 * SN + idx] = m;
    float mo = fmaxf(m + A0, B0);
    float ea = __expf(m + A0 - mo);
    float eb = __expf(B0 - mo);
    c = ea * c + eb * D0;
    n = ea * n + eb * N0;
    m = mo;
    A0 = A1; B0 = B1; D0 = D1; N0 = N1;
  }
}

// ---------------------------------------------------------------------------
// Kernel 4: pass 3 — read entering state, replay 32 steps of the original
// recurrence, write h. Last chunk writes finals. 262144 threads.
// ---------------------------------------------------------------------------
__global__ __launch_bounds__(256) void scan_pass3(
    const u16* __restrict__ gz16, const float* __restrict__ gi,
    const float* __restrict__ gf, const u16* __restrict__ go16,
    const float* __restrict__ ent, float* __restrict__ out) {
  const int t  = blockIdx.x * 256 + threadIdx.x;
  const int ch = t & (NCH - 1);
  const int ck = t >> 12;

  const size_t idx0 = (size_t)ck * NCH + ch;
  float c = ent[idx0];
  float n = ent[SN + idx0];
  float m = ent[2 * SN + idx0];

  const int b = ch >> 10, d = ch & 1023;
  const size_t base = (size_t)ck * CHUNK * NCH + ch;
  float* hout = out + (size_t)b * (S_LEN * 1024) + (size_t)(ck * CHUNK) * 1024 + d;

  float hv = 0.f;
  float z0[8], i0[8], f0[8], o0[8], z1[8], i1[8], f1[8], o1[8];
#pragma unroll
  for (int j = 0; j < 8; ++j) {
    size_t off = base + (size_t)j * NCH;
    z0[j] = bf2f(gz16[off]); i0[j] = gi[off]; f0[j] = gf[off]; o0[j] = bf2f(go16[off]);
  }

  auto step = [&](float z, float i, float f, float o, int s) {
    float mn = fmaxf(f + m, i);
    float fh = __expf(f + m - mn);
    float ih = __expf(i - mn);
    c = fh * c + ih * z;
    n = fh * n + ih;
    m = mn;
    hv = o * c * __builtin_amdgcn_rcpf(n + EPS);
    hout[(size_t)s * 1024] = hv;
  };

  for (int gb = 0; gb < 4; gb += 2) {
#pragma unroll
    for (int j = 0; j < 8; ++j) {
      size_t off = base + (size_t)((gb + 1) * 8 + j) * NCH;
      z1[j] = bf2f(gz16[off]); i1[j] = gi[off]; f1[j] = gf[off]; o1[j] = bf2f(go16[off]);
    }
#pragma unroll
    for (int j = 0; j < 8; ++j) step(z0[j], i0[j], f0[j], o0[j], gb * 8 + j);
    if (gb + 2 < 4) {
#pragma unroll
      for (int j = 0; j < 8; ++j) {
        size_t off = base + (size_t)((gb + 2) * 8 + j) * NCH;
        z0[j] = bf2f(gz16[off]); i0[j] = gi[off]; f0[j] = gf[off]; o0[j] = bf2f(go16[off]);
      }
    }
#pragma unroll
    for (int j = 0; j < 8; ++j) step(z1[j], i1[j], f1[j], o1[j], (gb + 1) * 8 + j);
  }

  if (ck == NCHUNK - 1) {
    float* fin = out + (size_t)BATCH * S_LEN * 1024;   // 8,388,608
    fin[ch]            = hv;
    fin[NCH + ch]      = c;
    fin[2 * NCH + ch]  = n;
    fin[3 * NCH + ch]  = m;
  }
}

extern "C" void kernel_launch(void* const* d_in, const int* in_sizes, int n_in,
                              void* d_out, int out_size, void* d_ws, size_t ws_size,
                              hipStream_t stream) {
  const float* x    = (const float*)d_in[0];   // [4,2048,4096] fp32
  const float* W    = (const float*)d_in[1];   // [4,4,256,256] fp32
  const float* bias = (const float*)d_in[2];   // [4,4,256] fp32
  float* out = (float*)d_out;

  // ws layout: z bf16 | i fp32 | f fp32 | o bf16 | sums 4*SN | ent 3*SN
  u16*   gz16 = (u16*)d_ws;                       // 16.78 MB
  float* gi   = (float*)(gz16 + PLANE);           // 33.55 MB
  float* gf   = gi + PLANE;                       // 33.55 MB
  u16*   go16 = (u16*)(gf + PLANE);               // 16.78 MB
  float* sums = (float*)(go16 + PLANE);           // 4.19 MB
  float* ent  = sums + 4 * SN;                    // 3.15 MB  (total ~108 MB)

  gates_gemm3<<<dim3(16, 32), dim3(1024), 0, stream>>>(x, W, bias, gz16, gi, gf, go16);
  scan_pass1<<<dim3(1024), dim3(256), 0, stream>>>(gz16, gi, gf, sums);
  scan_pass2<<<dim3(16), dim3(256), 0, stream>>>(sums, ent);
  scan_pass3<<<dim3(1024), dim3(256), 0, stream>>>(gz16, gi, gf, go16, ent, out);
}